// Round 2
// baseline (303.701 us; speedup 1.0000x reference)
//
#include <hip/hip_runtime.h>
#include <hip/hip_bf16.h>

typedef __bf16 bf16x8 __attribute__((ext_vector_type(8)));
typedef __bf16 bf16x4 __attribute__((ext_vector_type(4)));
typedef float  f32x4  __attribute__((ext_vector_type(4)));

#define HID   256
#define BM    64
#define PITCH 264   // bf16 elems per LDS row (16B-aligned, breaks 512B bank stride)

// gate order: 0=ir 1=iz 2=in 3=hz 4=hn
// ---- prepack weights fp32 -> bf16 in MFMA-fragment order --------------------
// fragment (ks,g,cb): lane l, elem j = W_g[cb*16 + (l&15)][ks*32 + (l>>4)*8 + j]
// stored at wb[((ks*5+g)*16+cb)*512 + l*8 + j]  -> each fragment = 1KB contiguous
__global__ void __launch_bounds__(256) prepack_frag(
    const float* __restrict__ w0, const float* __restrict__ w1,
    const float* __restrict__ w2, const float* __restrict__ w3,
    const float* __restrict__ w4, __bf16* __restrict__ wb)
{
    int t    = blockIdx.x * 256 + threadIdx.x;   // 40960 total
    int lane = t & 63;
    int cb   = (t >> 6) & 15;
    int gk   = t >> 10;                          // ks*5 + g
    int g    = gk % 5;
    int ks   = gk / 5;
    const float* W = g == 0 ? w0 : g == 1 ? w1 : g == 2 ? w2 : g == 3 ? w3 : w4;
    int row = cb * 16 + (lane & 15);
    int k0  = ks * 32 + (lane >> 4) * 8;
    float4 p = *(const float4*)(W + row * HID + k0);
    float4 q = *(const float4*)(W + row * HID + k0 + 4);
    bf16x8 o;
    o[0]=(__bf16)p.x; o[1]=(__bf16)p.y; o[2]=(__bf16)p.z; o[3]=(__bf16)p.w;
    o[4]=(__bf16)q.x; o[5]=(__bf16)q.y; o[6]=(__bf16)q.z; o[7]=(__bf16)q.w;
    *(bf16x8*)(wb + (size_t)t * 8) = o;
}

// ---- fused GRU cell ---------------------------------------------------------
// 8 waves/block, wave wn owns 64 rows x cols [wn*32, wn*32+32)
// acc sets: z = iz+hz, r = ir+hz, nx = in, nh = hn  (bias added in epilogue)
template<bool PACKED>
__global__ void __launch_bounds__(512, 4) gru_fused(
    const float* __restrict__ x,  const float* __restrict__ h,
    const __bf16* __restrict__ wb,
    const float* __restrict__ w_ir, const float* __restrict__ w_iz,
    const float* __restrict__ w_in, const float* __restrict__ w_hz,
    const float* __restrict__ w_hn,
    const float* __restrict__ b_ir, const float* __restrict__ b_iz,
    const float* __restrict__ b_in, const float* __restrict__ b_hz,
    const float* __restrict__ b_hn,
    float* __restrict__ out)
{
    __shared__ __bf16 xt[BM * PITCH];
    __shared__ __bf16 ht[BM * PITCH];

    const int t    = threadIdx.x;
    const int row0 = blockIdx.x * BM;

    // ---- stage x,h tiles (fp32 -> bf16) into LDS ----------------------------
#pragma unroll
    for (int i = 0; i < 8; ++i) {
        int c  = i * 512 + t;
        int r  = c >> 6;
        int k4 = (c & 63) * 4;
        float4 vx = *(const float4*)(x + (size_t)(row0 + r) * HID + k4);
        float4 vh = *(const float4*)(h + (size_t)(row0 + r) * HID + k4);
        bf16x4 bx, bh;
        bx[0] = (__bf16)vx.x; bx[1] = (__bf16)vx.y; bx[2] = (__bf16)vx.z; bx[3] = (__bf16)vx.w;
        bh[0] = (__bf16)vh.x; bh[1] = (__bf16)vh.y; bh[2] = (__bf16)vh.z; bh[3] = (__bf16)vh.w;
        *(bf16x4*)(xt + r * PITCH + k4) = bx;
        *(bf16x4*)(ht + r * PITCH + k4) = bh;
    }
    __syncthreads();

    const int lane = t & 63;
    const int wn   = t >> 6;      // 0..7 : col slice
    const int lr   = lane & 15;
    const int lg   = lane >> 4;

    f32x4 az[4][2], ar[4][2], anx[4][2], anh[4][2];   // [mf][nf]
#pragma unroll
    for (int mf = 0; mf < 4; ++mf)
#pragma unroll
        for (int nf = 0; nf < 2; ++nf) {
            az[mf][nf] = (f32x4)0.0f; ar[mf][nf] = (f32x4)0.0f;
            anx[mf][nf] = (f32x4)0.0f; anh[mf][nf] = (f32x4)0.0f;
        }

    const float* wsrc[5] = { w_ir, w_iz, w_in, w_hz, w_hn };
    const __bf16* wbase = wb + wn * 1024 + lane * 8;   // + (ks*5+g)*8192 + nf*512

    // ---- K loop: 8 K-steps of 32 --------------------------------------------
#pragma unroll
    for (int ks = 0; ks < 8; ++ks) {
        bf16x8 ax[4], ah[4];
#pragma unroll
        for (int mf = 0; mf < 4; ++mf) {
            int off = (mf * 16 + lr) * PITCH + ks * 32 + lg * 8;
            ax[mf] = *(const bf16x8*)(xt + off);
            ah[mf] = *(const bf16x8*)(ht + off);
        }
        bf16x8 b[5][2];
#pragma unroll
        for (int nf = 0; nf < 2; ++nf) {
#pragma unroll
            for (int g = 0; g < 5; ++g) {
                if (PACKED) {
                    b[g][nf] = *(const bf16x8*)(wbase + (ks * 5 + g) * 8192 + nf * 512);
                } else {
                    int cb = wn * 2 + nf;
                    const float* pp = wsrc[g] + (cb * 16 + lr) * HID + ks * 32 + lg * 8;
                    float4 p = *(const float4*)(pp);
                    float4 q = *(const float4*)(pp + 4);
                    bf16x8 o;
                    o[0]=(__bf16)p.x; o[1]=(__bf16)p.y; o[2]=(__bf16)p.z; o[3]=(__bf16)p.w;
                    o[4]=(__bf16)q.x; o[5]=(__bf16)q.y; o[6]=(__bf16)q.z; o[7]=(__bf16)q.w;
                    b[g][nf] = o;
                }
            }
        }
#pragma unroll
        for (int nf = 0; nf < 2; ++nf)
#pragma unroll
            for (int mf = 0; mf < 4; ++mf) {
                az[mf][nf]  = __builtin_amdgcn_mfma_f32_16x16x32_bf16(ax[mf], b[1][nf], az[mf][nf], 0, 0, 0);
                az[mf][nf]  = __builtin_amdgcn_mfma_f32_16x16x32_bf16(ah[mf], b[3][nf], az[mf][nf], 0, 0, 0);
                ar[mf][nf]  = __builtin_amdgcn_mfma_f32_16x16x32_bf16(ax[mf], b[0][nf], ar[mf][nf], 0, 0, 0);
                ar[mf][nf]  = __builtin_amdgcn_mfma_f32_16x16x32_bf16(ah[mf], b[3][nf], ar[mf][nf], 0, 0, 0);
                anx[mf][nf] = __builtin_amdgcn_mfma_f32_16x16x32_bf16(ax[mf], b[2][nf], anx[mf][nf], 0, 0, 0);
                anh[mf][nf] = __builtin_amdgcn_mfma_f32_16x16x32_bf16(ah[mf], b[4][nf], anh[mf][nf], 0, 0, 0);
            }
    }

    // ---- epilogue: gate fusion, write h_new ---------------------------------
    float bz[2], br[2], bnx[2], bnh[2];
#pragma unroll
    for (int nf = 0; nf < 2; ++nf) {
        int col = wn * 32 + nf * 16 + lr;
        bz[nf]  = b_iz[col] + b_hz[col];
        br[nf]  = b_ir[col] + b_hz[col];
        bnx[nf] = b_in[col];
        bnh[nf] = b_hn[col];
    }
#pragma unroll
    for (int mf = 0; mf < 4; ++mf)
#pragma unroll
        for (int nf = 0; nf < 2; ++nf)
#pragma unroll
            for (int i = 0; i < 4; ++i) {
                int rl  = mf * 16 + lg * 4 + i;          // C/D: row=(lane>>4)*4+i
                int col = wn * 32 + nf * 16 + lr;        //      col=lane&15
                float z  = 1.0f / (1.0f + __expf(-(az[mf][nf][i] + bz[nf])));
                float r  = 1.0f / (1.0f + __expf(-(ar[mf][nf][i] + br[nf])));
                float e2 = __expf(2.0f * (anx[mf][nf][i] + bnx[nf] + r * (anh[mf][nf][i] + bnh[nf])));
                float g  = 1.0f - 2.0f / (e2 + 1.0f);    // tanh
                float hp = (float)ht[rl * PITCH + col];
                out[(size_t)(row0 + rl) * HID + col] = (1.0f - z) * g + z * hp;
            }
}

extern "C" void kernel_launch(void* const* d_in, const int* in_sizes, int n_in,
                              void* d_out, int out_size, void* d_ws, size_t ws_size,
                              hipStream_t stream) {
    const float* x    = (const float*)d_in[0];
    const float* h    = (const float*)d_in[1];
    const float* w_ir = (const float*)d_in[2];
    const float* b_ir = (const float*)d_in[3];
    const float* w_iz = (const float*)d_in[4];
    const float* b_iz = (const float*)d_in[5];
    const float* w_in = (const float*)d_in[6];
    const float* b_in = (const float*)d_in[7];
    const float* w_hz = (const float*)d_in[8];
    const float* b_hz = (const float*)d_in[9];
    const float* w_hn = (const float*)d_in[10];
    const float* b_hn = (const float*)d_in[11];
    float* out = (float*)d_out;

    const int B = in_sizes[0] / HID;                                  // 65536
    const size_t wb_bytes = (size_t)5 * HID * HID * sizeof(__bf16);   // 640 KB

    if (ws_size >= wb_bytes) {
        __bf16* wb = (__bf16*)d_ws;
        prepack_frag<<<160, 256, 0, stream>>>(w_ir, w_iz, w_in, w_hz, w_hn, wb);
        gru_fused<true><<<B / BM, 512, 0, stream>>>(
            x, h, wb, nullptr, nullptr, nullptr, nullptr, nullptr,
            b_ir, b_iz, b_in, b_hz, b_hn, out);
    } else {
        gru_fused<false><<<B / BM, 512, 0, stream>>>(
            x, h, nullptr, w_ir, w_iz, w_in, w_hz, w_hn,
            b_ir, b_iz, b_in, b_hz, b_hn, out);
    }
}

// Round 3
// 99.216 us; speedup vs baseline: 3.0610x; 3.0610x over previous
//
#include <hip/hip_runtime.h>
#include <hip/hip_bf16.h>

typedef __bf16 bf16x8 __attribute__((ext_vector_type(8)));
typedef __bf16 bf16x4 __attribute__((ext_vector_type(4)));
typedef float  f32x4  __attribute__((ext_vector_type(4)));

#define HID   256
#define BM    32
#define PITCH 264   // bf16 elems per LDS row (16B-aligned, breaks 512B bank stride)

// gate order: 0=ir 1=iz 2=in 3=hz 4=hn
// ---- prepack weights fp32 -> bf16 in MFMA-fragment order --------------------
// fragment (ks,g,cb): lane l, elem j = W_g[cb*16 + (l&15)][ks*32 + (l>>4)*8 + j]
// stored at wb[((ks*5+g)*16+cb)*512 + l*8 + j]  -> each fragment = 1KB contiguous
__global__ void __launch_bounds__(256) prepack_frag(
    const float* __restrict__ w0, const float* __restrict__ w1,
    const float* __restrict__ w2, const float* __restrict__ w3,
    const float* __restrict__ w4, __bf16* __restrict__ wb)
{
    int t    = blockIdx.x * 256 + threadIdx.x;   // 40960 total
    int lane = t & 63;
    int cb   = (t >> 6) & 15;
    int gk   = t >> 10;                          // ks*5 + g
    int g    = gk % 5;
    int ks   = gk / 5;
    const float* W = g == 0 ? w0 : g == 1 ? w1 : g == 2 ? w2 : g == 3 ? w3 : w4;
    int row = cb * 16 + (lane & 15);
    int k0  = ks * 32 + (lane >> 4) * 8;
    float4 p = *(const float4*)(W + row * HID + k0);
    float4 q = *(const float4*)(W + row * HID + k0 + 4);
    bf16x8 o;
    o[0]=(__bf16)p.x; o[1]=(__bf16)p.y; o[2]=(__bf16)p.z; o[3]=(__bf16)p.w;
    o[4]=(__bf16)q.x; o[5]=(__bf16)q.y; o[6]=(__bf16)q.z; o[7]=(__bf16)q.w;
    *(bf16x8*)(wb + (size_t)t * 8) = o;
}

// ---- fused GRU cell ---------------------------------------------------------
// BM=32 rows/block, 8 waves; wave wn owns all 32 rows x cols [wn*32, wn*32+32)
// acc sets (32x32 tile -> 64 VGPRs total): z = iz+hz, r = ir+hz, nx = in, nh = hn
template<bool PACKED>
__global__ void __launch_bounds__(512, 4) gru_fused(
    const float* __restrict__ x,  const float* __restrict__ h,
    const __bf16* __restrict__ wb,
    const float* __restrict__ w_ir, const float* __restrict__ w_iz,
    const float* __restrict__ w_in, const float* __restrict__ w_hz,
    const float* __restrict__ w_hn,
    const float* __restrict__ b_ir, const float* __restrict__ b_iz,
    const float* __restrict__ b_in, const float* __restrict__ b_hz,
    const float* __restrict__ b_hn,
    float* __restrict__ out)
{
    __shared__ __bf16 xt[BM * PITCH];   // 16.5 KB
    __shared__ __bf16 ht[BM * PITCH];

    const int t    = threadIdx.x;
    const int row0 = blockIdx.x * BM;

    // ---- stage x,h tiles (fp32 -> bf16) into LDS ----------------------------
#pragma unroll
    for (int i = 0; i < 4; ++i) {
        int c  = i * 512 + t;          // 2048 float4-chunks = 32 rows x 64
        int r  = c >> 6;
        int k4 = (c & 63) * 4;
        float4 vx = *(const float4*)(x + (size_t)(row0 + r) * HID + k4);
        float4 vh = *(const float4*)(h + (size_t)(row0 + r) * HID + k4);
        bf16x4 bx, bh;
        bx[0] = (__bf16)vx.x; bx[1] = (__bf16)vx.y; bx[2] = (__bf16)vx.z; bx[3] = (__bf16)vx.w;
        bh[0] = (__bf16)vh.x; bh[1] = (__bf16)vh.y; bh[2] = (__bf16)vh.z; bh[3] = (__bf16)vh.w;
        *(bf16x4*)(xt + r * PITCH + k4) = bx;
        *(bf16x4*)(ht + r * PITCH + k4) = bh;
    }
    __syncthreads();

    const int lane = t & 63;
    const int wn   = t >> 6;      // 0..7 : col slice
    const int lr   = lane & 15;
    const int lg   = lane >> 4;

    f32x4 az[2][2], ar[2][2], anx[2][2], anh[2][2];   // [mf][nf] -> 64 regs
#pragma unroll
    for (int mf = 0; mf < 2; ++mf)
#pragma unroll
        for (int nf = 0; nf < 2; ++nf) {
            az[mf][nf] = (f32x4)0.0f; ar[mf][nf] = (f32x4)0.0f;
            anx[mf][nf] = (f32x4)0.0f; anh[mf][nf] = (f32x4)0.0f;
        }

    const float* wsrc[5] = { w_ir, w_iz, w_in, w_hz, w_hn };
    const __bf16* wbase = wb + wn * 1024 + lane * 8;   // + (ks*5+g)*8192 + nf*512

    // ---- K loop: 8 K-steps of 32, gate-sequential to keep live frags low ----
#pragma unroll
    for (int ks = 0; ks < 8; ++ks) {
        bf16x8 ax[2], ah[2];
#pragma unroll
        for (int mf = 0; mf < 2; ++mf) {
            int off = (mf * 16 + lr) * PITCH + ks * 32 + lg * 8;
            ax[mf] = *(const bf16x8*)(xt + off);
            ah[mf] = *(const bf16x8*)(ht + off);
        }

        bf16x8 bhz[2], bo[2];
#pragma unroll
        for (int nf = 0; nf < 2; ++nf) {
            if (PACKED) {
                bhz[nf] = *(const bf16x8*)(wbase + (ks * 5 + 3) * 8192 + nf * 512);
                bo[nf]  = *(const bf16x8*)(wbase + (ks * 5 + 1) * 8192 + nf * 512);
            } else {
                int cb = wn * 2 + nf;
                const float* p3 = wsrc[3] + (cb * 16 + lr) * HID + ks * 32 + lg * 8;
                const float* p1 = wsrc[1] + (cb * 16 + lr) * HID + ks * 32 + lg * 8;
                float4 a0 = *(const float4*)(p3), a1 = *(const float4*)(p3 + 4);
                float4 c0 = *(const float4*)(p1), c1 = *(const float4*)(p1 + 4);
                bf16x8 o, u;
                o[0]=(__bf16)a0.x; o[1]=(__bf16)a0.y; o[2]=(__bf16)a0.z; o[3]=(__bf16)a0.w;
                o[4]=(__bf16)a1.x; o[5]=(__bf16)a1.y; o[6]=(__bf16)a1.z; o[7]=(__bf16)a1.w;
                u[0]=(__bf16)c0.x; u[1]=(__bf16)c0.y; u[2]=(__bf16)c0.z; u[3]=(__bf16)c0.w;
                u[4]=(__bf16)c1.x; u[5]=(__bf16)c1.y; u[6]=(__bf16)c1.z; u[7]=(__bf16)c1.w;
                bhz[nf] = o; bo[nf] = u;
            }
        }
#pragma unroll
        for (int nf = 0; nf < 2; ++nf)
#pragma unroll
            for (int mf = 0; mf < 2; ++mf) {
                az[mf][nf] = __builtin_amdgcn_mfma_f32_16x16x32_bf16(ax[mf], bo[nf],  az[mf][nf], 0, 0, 0);
                az[mf][nf] = __builtin_amdgcn_mfma_f32_16x16x32_bf16(ah[mf], bhz[nf], az[mf][nf], 0, 0, 0);
            }

#pragma unroll
        for (int nf = 0; nf < 2; ++nf) {
            if (PACKED) {
                bo[nf] = *(const bf16x8*)(wbase + (ks * 5 + 0) * 8192 + nf * 512);
            } else {
                int cb = wn * 2 + nf;
                const float* p0 = wsrc[0] + (cb * 16 + lr) * HID + ks * 32 + lg * 8;
                float4 c0 = *(const float4*)(p0), c1 = *(const float4*)(p0 + 4);
                bf16x8 u;
                u[0]=(__bf16)c0.x; u[1]=(__bf16)c0.y; u[2]=(__bf16)c0.z; u[3]=(__bf16)c0.w;
                u[4]=(__bf16)c1.x; u[5]=(__bf16)c1.y; u[6]=(__bf16)c1.z; u[7]=(__bf16)c1.w;
                bo[nf] = u;
            }
        }
#pragma unroll
        for (int nf = 0; nf < 2; ++nf)
#pragma unroll
            for (int mf = 0; mf < 2; ++mf) {
                ar[mf][nf] = __builtin_amdgcn_mfma_f32_16x16x32_bf16(ax[mf], bo[nf],  ar[mf][nf], 0, 0, 0);
                ar[mf][nf] = __builtin_amdgcn_mfma_f32_16x16x32_bf16(ah[mf], bhz[nf], ar[mf][nf], 0, 0, 0);
            }

#pragma unroll
        for (int nf = 0; nf < 2; ++nf) {
            if (PACKED) {
                bo[nf] = *(const bf16x8*)(wbase + (ks * 5 + 2) * 8192 + nf * 512);
            } else {
                int cb = wn * 2 + nf;
                const float* p2 = wsrc[2] + (cb * 16 + lr) * HID + ks * 32 + lg * 8;
                float4 c0 = *(const float4*)(p2), c1 = *(const float4*)(p2 + 4);
                bf16x8 u;
                u[0]=(__bf16)c0.x; u[1]=(__bf16)c0.y; u[2]=(__bf16)c0.z; u[3]=(__bf16)c0.w;
                u[4]=(__bf16)c1.x; u[5]=(__bf16)c1.y; u[6]=(__bf16)c1.z; u[7]=(__bf16)c1.w;
                bo[nf] = u;
            }
        }
#pragma unroll
        for (int nf = 0; nf < 2; ++nf)
#pragma unroll
            for (int mf = 0; mf < 2; ++mf)
                anx[mf][nf] = __builtin_amdgcn_mfma_f32_16x16x32_bf16(ax[mf], bo[nf], anx[mf][nf], 0, 0, 0);

#pragma unroll
        for (int nf = 0; nf < 2; ++nf) {
            if (PACKED) {
                bo[nf] = *(const bf16x8*)(wbase + (ks * 5 + 4) * 8192 + nf * 512);
            } else {
                int cb = wn * 2 + nf;
                const float* p4 = wsrc[4] + (cb * 16 + lr) * HID + ks * 32 + lg * 8;
                float4 c0 = *(const float4*)(p4), c1 = *(const float4*)(p4 + 4);
                bf16x8 u;
                u[0]=(__bf16)c0.x; u[1]=(__bf16)c0.y; u[2]=(__bf16)c0.z; u[3]=(__bf16)c0.w;
                u[4]=(__bf16)c1.x; u[5]=(__bf16)c1.y; u[6]=(__bf16)c1.z; u[7]=(__bf16)c1.w;
                bo[nf] = u;
            }
        }
#pragma unroll
        for (int nf = 0; nf < 2; ++nf)
#pragma unroll
            for (int mf = 0; mf < 2; ++mf)
                anh[mf][nf] = __builtin_amdgcn_mfma_f32_16x16x32_bf16(ah[mf], bo[nf], anh[mf][nf], 0, 0, 0);
    }

    // ---- epilogue: gate fusion, write h_new ---------------------------------
    float bz[2], br[2], bnx[2], bnh[2];
#pragma unroll
    for (int nf = 0; nf < 2; ++nf) {
        int col = wn * 32 + nf * 16 + lr;
        bz[nf]  = b_iz[col] + b_hz[col];
        br[nf]  = b_ir[col] + b_hz[col];
        bnx[nf] = b_in[col];
        bnh[nf] = b_hn[col];
    }
#pragma unroll
    for (int mf = 0; mf < 2; ++mf)
#pragma unroll
        for (int nf = 0; nf < 2; ++nf)
#pragma unroll
            for (int i = 0; i < 4; ++i) {
                int rl  = mf * 16 + lg * 4 + i;          // C/D: row=(lane>>4)*4+i
                int col = wn * 32 + nf * 16 + lr;        //      col=lane&15
                float z  = 1.0f / (1.0f + __expf(-(az[mf][nf][i] + bz[nf])));
                float r  = 1.0f / (1.0f + __expf(-(ar[mf][nf][i] + br[nf])));
                float e2 = __expf(2.0f * (anx[mf][nf][i] + bnx[nf] + r * (anh[mf][nf][i] + bnh[nf])));
                float g  = 1.0f - 2.0f / (e2 + 1.0f);    // tanh
                float hp = (float)ht[rl * PITCH + col];
                out[(size_t)(row0 + rl) * HID + col] = (1.0f - z) * g + z * hp;
            }
}

extern "C" void kernel_launch(void* const* d_in, const int* in_sizes, int n_in,
                              void* d_out, int out_size, void* d_ws, size_t ws_size,
                              hipStream_t stream) {
    const float* x    = (const float*)d_in[0];
    const float* h    = (const float*)d_in[1];
    const float* w_ir = (const float*)d_in[2];
    const float* b_ir = (const float*)d_in[3];
    const float* w_iz = (const float*)d_in[4];
    const float* b_iz = (const float*)d_in[5];
    const float* w_in = (const float*)d_in[6];
    const float* b_in = (const float*)d_in[7];
    const float* w_hz = (const float*)d_in[8];
    const float* b_hz = (const float*)d_in[9];
    const float* w_hn = (const float*)d_in[10];
    const float* b_hn = (const float*)d_in[11];
    float* out = (float*)d_out;

    const int B = in_sizes[0] / HID;                                  // 65536
    const size_t wb_bytes = (size_t)5 * HID * HID * sizeof(__bf16);   // 640 KB

    if (ws_size >= wb_bytes) {
        __bf16* wb = (__bf16*)d_ws;
        prepack_frag<<<160, 256, 0, stream>>>(w_ir, w_iz, w_in, w_hz, w_hn, wb);
        gru_fused<true><<<B / BM, 512, 0, stream>>>(
            x, h, wb, nullptr, nullptr, nullptr, nullptr, nullptr,
            b_ir, b_iz, b_in, b_hz, b_hn, out);
    } else {
        gru_fused<false><<<B / BM, 512, 0, stream>>>(
            x, h, nullptr, w_ir, w_iz, w_in, w_hz, w_hn,
            b_ir, b_iz, b_in, b_hz, b_hn, out);
    }
}

// Round 4
// 98.071 us; speedup vs baseline: 3.0968x; 1.0117x over previous
//
#include <hip/hip_runtime.h>
#include <hip/hip_bf16.h>

typedef __bf16 bf16x8 __attribute__((ext_vector_type(8)));
typedef __bf16 bf16x4 __attribute__((ext_vector_type(4)));
typedef float  f32x4  __attribute__((ext_vector_type(4)));

#define HID   256
#define BM    64
#define PITCH 264   // bf16 elems per LDS row (16B-aligned, breaks 512B bank stride)

// gate order: 0=ir 1=iz 2=in 3=hz 4=hn
// ---- prepack weights fp32 -> bf16 in MFMA-fragment order --------------------
// fragment (ks,g,cb): lane l, elem j = W_g[cb*16 + (l&15)][ks*32 + (l>>4)*8 + j]
// stored at wb[((ks*5+g)*16+cb)*512 + l*8 + j]  -> each fragment = 1KB contiguous
__global__ void __launch_bounds__(256) prepack_frag(
    const float* __restrict__ w0, const float* __restrict__ w1,
    const float* __restrict__ w2, const float* __restrict__ w3,
    const float* __restrict__ w4, __bf16* __restrict__ wb)
{
    int t    = blockIdx.x * 256 + threadIdx.x;   // 40960 total
    int lane = t & 63;
    int cb   = (t >> 6) & 15;
    int gk   = t >> 10;                          // ks*5 + g
    int g    = gk % 5;
    int ks   = gk / 5;
    const float* W = g == 0 ? w0 : g == 1 ? w1 : g == 2 ? w2 : g == 3 ? w3 : w4;
    int row = cb * 16 + (lane & 15);
    int k0  = ks * 32 + (lane >> 4) * 8;
    float4 p = *(const float4*)(W + row * HID + k0);
    float4 q = *(const float4*)(W + row * HID + k0 + 4);
    bf16x8 o;
    o[0]=(__bf16)p.x; o[1]=(__bf16)p.y; o[2]=(__bf16)p.z; o[3]=(__bf16)p.w;
    o[4]=(__bf16)q.x; o[5]=(__bf16)q.y; o[6]=(__bf16)q.z; o[7]=(__bf16)q.w;
    *(bf16x8*)(wb + (size_t)t * 8) = o;
}

// ---- fused GRU cell ---------------------------------------------------------
// BM=64 rows/block, 8 waves; wave wn owns all 64 rows x cols [wn*32, wn*32+32)
// 256-reg tier (2 waves/SIMD): acc 128 AGPR + 1-K-step-deep B-frag prefetch.
template<bool PACKED>
__global__ void __launch_bounds__(512, 2) gru_fused(
    const float* __restrict__ x,  const float* __restrict__ h,
    const __bf16* __restrict__ wb,
    const float* __restrict__ w_ir, const float* __restrict__ w_iz,
    const float* __restrict__ w_in, const float* __restrict__ w_hz,
    const float* __restrict__ w_hn,
    const float* __restrict__ b_ir, const float* __restrict__ b_iz,
    const float* __restrict__ b_in, const float* __restrict__ b_hz,
    const float* __restrict__ b_hn,
    float* __restrict__ out)
{
    __shared__ __bf16 xt[BM * PITCH];   // 33 KB
    __shared__ __bf16 ht[BM * PITCH];   // 33 KB

    const int t    = threadIdx.x;
    const int row0 = blockIdx.x * BM;
    const int lane = t & 63;
    const int wn   = t >> 6;      // 0..7 : col slice
    const int lr   = lane & 15;
    const int lg   = lane >> 4;

    const float* wsrc[5] = { w_ir, w_iz, w_in, w_hz, w_hn };
    const __bf16* wbase = wb + wn * 1024 + lane * 8;   // + (ks*5+g)*8192 + nf*512

    // ---- prologue: issue x/h HBM loads, then B(ks=0) L2 loads, then convert -
    float4 vx[8], vh[8];
#pragma unroll
    for (int i = 0; i < 8; ++i) {
        int c = i * 512 + t, r = c >> 6, k4 = (c & 63) * 4;
        vx[i] = *(const float4*)(x + (size_t)(row0 + r) * HID + k4);
        vh[i] = *(const float4*)(h + (size_t)(row0 + r) * HID + k4);
    }
    bf16x8 Bc[10];
    if (PACKED) {
#pragma unroll
        for (int g = 0; g < 5; ++g)
#pragma unroll
            for (int nf = 0; nf < 2; ++nf)
                Bc[g * 2 + nf] = *(const bf16x8*)(wbase + g * 8192 + nf * 512);
    }
#pragma unroll
    for (int i = 0; i < 8; ++i) {
        int c = i * 512 + t, r = c >> 6, k4 = (c & 63) * 4;
        bf16x4 bx, bh;
        bx[0] = (__bf16)vx[i].x; bx[1] = (__bf16)vx[i].y; bx[2] = (__bf16)vx[i].z; bx[3] = (__bf16)vx[i].w;
        bh[0] = (__bf16)vh[i].x; bh[1] = (__bf16)vh[i].y; bh[2] = (__bf16)vh[i].z; bh[3] = (__bf16)vh[i].w;
        *(bf16x4*)(xt + r * PITCH + k4) = bx;
        *(bf16x4*)(ht + r * PITCH + k4) = bh;
    }
    __syncthreads();

    f32x4 az[4][2], ar[4][2], anx[4][2], anh[4][2];   // [mf][nf] -> 128 regs
#pragma unroll
    for (int mf = 0; mf < 4; ++mf)
#pragma unroll
        for (int nf = 0; nf < 2; ++nf) {
            az[mf][nf] = (f32x4)0.0f; ar[mf][nf] = (f32x4)0.0f;
            anx[mf][nf] = (f32x4)0.0f; anh[mf][nf] = (f32x4)0.0f;
        }

    // ---- K loop: 8 K-steps of 32, B-frags prefetched one K-step ahead -------
#pragma unroll
    for (int ks = 0; ks < 8; ++ks) {
        bf16x8 ax[4], ah[4];
#pragma unroll
        for (int mf = 0; mf < 4; ++mf) {
            int off = (mf * 16 + lr) * PITCH + ks * 32 + lg * 8;
            ax[mf] = *(const bf16x8*)(xt + off);
            ah[mf] = *(const bf16x8*)(ht + off);
        }

        bf16x8 Bn[10];
        if (PACKED) {
            if (ks < 7) {
#pragma unroll
                for (int g = 0; g < 5; ++g)
#pragma unroll
                    for (int nf = 0; nf < 2; ++nf)
                        Bn[g * 2 + nf] = *(const bf16x8*)(wbase + ((ks + 1) * 5 + g) * 8192 + nf * 512);
            }
        } else {
            // fallback: load fp32 weights JIT, convert
#pragma unroll
            for (int g = 0; g < 5; ++g)
#pragma unroll
                for (int nf = 0; nf < 2; ++nf) {
                    const float* pp = wsrc[g] + ((wn * 2 + nf) * 16 + lr) * HID + ks * 32 + lg * 8;
                    float4 c0 = *(const float4*)(pp), c1 = *(const float4*)(pp + 4);
                    bf16x8 u;
                    u[0]=(__bf16)c0.x; u[1]=(__bf16)c0.y; u[2]=(__bf16)c0.z; u[3]=(__bf16)c0.w;
                    u[4]=(__bf16)c1.x; u[5]=(__bf16)c1.y; u[6]=(__bf16)c1.z; u[7]=(__bf16)c1.w;
                    Bc[g * 2 + nf] = u;
                }
        }
        __builtin_amdgcn_sched_barrier(0);   // pin load issue above the MFMA cluster

        // gate order 0=ir 1=iz 2=in 3=hz 4=hn ; Bc[g*2+nf]
#pragma unroll
        for (int nf = 0; nf < 2; ++nf)
#pragma unroll
            for (int mf = 0; mf < 4; ++mf) {
                az[mf][nf] = __builtin_amdgcn_mfma_f32_16x16x32_bf16(ax[mf], Bc[2 + nf], az[mf][nf], 0, 0, 0);
                az[mf][nf] = __builtin_amdgcn_mfma_f32_16x16x32_bf16(ah[mf], Bc[6 + nf], az[mf][nf], 0, 0, 0);
            }
#pragma unroll
        for (int nf = 0; nf < 2; ++nf)
#pragma unroll
            for (int mf = 0; mf < 4; ++mf) {
                ar[mf][nf] = __builtin_amdgcn_mfma_f32_16x16x32_bf16(ax[mf], Bc[0 + nf], ar[mf][nf], 0, 0, 0);
                ar[mf][nf] = __builtin_amdgcn_mfma_f32_16x16x32_bf16(ah[mf], Bc[6 + nf], ar[mf][nf], 0, 0, 0);
            }
#pragma unroll
        for (int nf = 0; nf < 2; ++nf)
#pragma unroll
            for (int mf = 0; mf < 4; ++mf)
                anx[mf][nf] = __builtin_amdgcn_mfma_f32_16x16x32_bf16(ax[mf], Bc[4 + nf], anx[mf][nf], 0, 0, 0);
#pragma unroll
        for (int nf = 0; nf < 2; ++nf)
#pragma unroll
            for (int mf = 0; mf < 4; ++mf)
                anh[mf][nf] = __builtin_amdgcn_mfma_f32_16x16x32_bf16(ah[mf], Bc[8 + nf], anh[mf][nf], 0, 0, 0);

        if (PACKED && ks < 7) {
#pragma unroll
            for (int j = 0; j < 10; ++j) Bc[j] = Bn[j];
        }
    }

    // ---- epilogue: gate fusion, write h_new ---------------------------------
    float bz[2], br[2], bnx[2], bnh[2];
#pragma unroll
    for (int nf = 0; nf < 2; ++nf) {
        int col = wn * 32 + nf * 16 + lr;
        bz[nf]  = b_iz[col] + b_hz[col];
        br[nf]  = b_ir[col] + b_hz[col];
        bnx[nf] = b_in[col];
        bnh[nf] = b_hn[col];
    }
#pragma unroll
    for (int mf = 0; mf < 4; ++mf)
#pragma unroll
        for (int nf = 0; nf < 2; ++nf)
#pragma unroll
            for (int i = 0; i < 4; ++i) {
                int rl  = mf * 16 + lg * 4 + i;          // C/D: row=(lane>>4)*4+i
                int col = wn * 32 + nf * 16 + lr;        //      col=lane&15
                float z  = 1.0f / (1.0f + __expf(-(az[mf][nf][i] + bz[nf])));
                float r  = 1.0f / (1.0f + __expf(-(ar[mf][nf][i] + br[nf])));
                float e2 = __expf(2.0f * (anx[mf][nf][i] + bnx[nf] + r * (anh[mf][nf][i] + bnh[nf])));
                float g  = 1.0f - 2.0f / (e2 + 1.0f);    // tanh
                float hp = (float)ht[rl * PITCH + col];
                out[(size_t)(row0 + rl) * HID + col] = (1.0f - z) * g + z * hp;
            }
}

extern "C" void kernel_launch(void* const* d_in, const int* in_sizes, int n_in,
                              void* d_out, int out_size, void* d_ws, size_t ws_size,
                              hipStream_t stream) {
    const float* x    = (const float*)d_in[0];
    const float* h    = (const float*)d_in[1];
    const float* w_ir = (const float*)d_in[2];
    const float* b_ir = (const float*)d_in[3];
    const float* w_iz = (const float*)d_in[4];
    const float* b_iz = (const float*)d_in[5];
    const float* w_in = (const float*)d_in[6];
    const float* b_in = (const float*)d_in[7];
    const float* w_hz = (const float*)d_in[8];
    const float* b_hz = (const float*)d_in[9];
    const float* w_hn = (const float*)d_in[10];
    const float* b_hn = (const float*)d_in[11];
    float* out = (float*)d_out;

    const int B = in_sizes[0] / HID;                                  // 65536
    const size_t wb_bytes = (size_t)5 * HID * HID * sizeof(__bf16);   // 640 KB

    if (ws_size >= wb_bytes) {
        __bf16* wb = (__bf16*)d_ws;
        prepack_frag<<<160, 256, 0, stream>>>(w_ir, w_iz, w_in, w_hz, w_hn, wb);
        gru_fused<true><<<B / BM, 512, 0, stream>>>(
            x, h, wb, nullptr, nullptr, nullptr, nullptr, nullptr,
            b_ir, b_iz, b_in, b_hz, b_hn, out);
    } else {
        gru_fused<false><<<B / BM, 512, 0, stream>>>(
            x, h, nullptr, w_ir, w_iz, w_in, w_hz, w_hn,
            b_ir, b_iz, b_in, b_hz, b_hn, out);
    }
}